// Round 2
// baseline (2102.451 us; speedup 1.0000x reference)
//
#include <hip/hip_runtime.h>

// AttentionPooling, single-x-pass version.
//   s = tanh(x@W1+b1)@w2   (b2 dropped: constant shift cancels in softmax)
//   e = exp(s)             (NO max subtraction: |s| <= ||w2||_1 ~ 13, exp safe in fp32)
//   pooled_raw[b] += e*x ; denom[b] += e   (device-scope atomics, batch sorted ->
//                                           ~2 segment flushes per 256-row block)
//   out = (pooled_raw/denom) @ Wp + bp
// HBM traffic ~ 1.06 GB (x read once; re-read for pooling is L3-absorbed).

typedef __bf16 bf16_t;
typedef __attribute__((ext_vector_type(8))) __bf16 bf16x8;
typedef __attribute__((ext_vector_type(4))) float f32x4;

constexpr int D = 256;

// ---------------------------------------------------------------------------
// One prep kernel: zero pooled_raw (B*D) + denom (B), and repack W1 into bf16
// MFMA B-fragment order: tile j (16 cols), k-step kk (32 k), lane:
//   k = kk*32 + (lane>>4)*8 + t, n = j*16 + (lane&15).
__global__ void prep_kernel(const float* __restrict__ W1,
                            bf16_t* __restrict__ wfrag,
                            float* __restrict__ pooled_raw,
                            float* __restrict__ denom, int B) {
    int tid = blockIdx.x * blockDim.x + threadIdx.x;  // grid covers B*D/4 threads
    if (tid < B * D / 4) ((float4*)pooled_raw)[tid] = make_float4(0.f, 0.f, 0.f, 0.f);
    if (tid < B / 4) ((float4*)denom)[tid] = make_float4(0.f, 0.f, 0.f, 0.f);
    if (tid < 16 * 8 * 64) {
        int lane = tid & 63;
        int kk   = (tid >> 6) & 7;
        int j    = tid >> 9;
        int quad = lane >> 4, col = lane & 15;
        const float* src = W1 + (size_t)(kk * 32 + quad * 8) * D + j * 16 + col;
        bf16_t* dst = wfrag + (size_t)tid * 8;
#pragma unroll
        for (int t = 0; t < 8; ++t) dst[t] = (bf16_t)src[(size_t)t * D];
    }
}

// ---------------------------------------------------------------------------
// Fused score+pool: 256 rows/block, 4 waves x 64 rows (4 strips of 16).
// Phase 1: MFMA h = x@W1, epilogue e = exp(tanh(h+b1)@w2) -> LDS.
// Phase 2: all 256 threads (thread t = feature t) walk the block's 256 rows
// (x re-read hits L3), accumulate e*x, flush to global atomics at segment
// boundaries (batch sorted -> wave-uniform flush branch).
__global__ __launch_bounds__(256, 2) void fused_kernel(
    const float* __restrict__ x, const int* __restrict__ batch,
    const bf16_t* __restrict__ wfrag, const float* __restrict__ b1,
    const float* __restrict__ w2, float* __restrict__ pooled_raw,
    float* __restrict__ denom, int N) {
    const int lane = threadIdx.x & 63;
    const int wave = threadIdx.x >> 6;
    const int quad = lane >> 4;
    const int col  = lane & 15;
    const int bb   = blockIdx.x * 256;           // block base row
    const long base = (long)bb + wave * 64;      // wave base row

    __shared__ float e_lds[256];
    __shared__ int   batch_lds[257];

    {   // stage batch (clamped; padded rows get e=0 below so dups are inert)
        int t = threadIdx.x;
        long r = bb + t; if (r >= N) r = N - 1;
        batch_lds[t] = batch[r];
        if (t == 0) {
            long r2 = bb + 255; if (r2 >= N) r2 = N - 1;
            batch_lds[256] = batch[r2];
        }
    }

    // ---- Phase 1: load A fragments (A[m=lane&15][k=quad*8+t], block kk) ----
    bf16x8 A[4][8];
#pragma unroll
    for (int st = 0; st < 4; ++st) {
        long row = base + st * 16 + col;
        if (row >= N) row = N - 1;
        const float* xp = x + row * (long)D + quad * 8;
#pragma unroll
        for (int kk = 0; kk < 8; ++kk) {
            float4 u0 = *(const float4*)(xp + kk * 32);
            float4 u1 = *(const float4*)(xp + kk * 32 + 4);
            bf16x8 a;
            a[0] = (bf16_t)u0.x; a[1] = (bf16_t)u0.y;
            a[2] = (bf16_t)u0.z; a[3] = (bf16_t)u0.w;
            a[4] = (bf16_t)u1.x; a[5] = (bf16_t)u1.y;
            a[6] = (bf16_t)u1.z; a[7] = (bf16_t)u1.w;
            A[st][kk] = a;
        }
    }

    float spart[4][4];
#pragma unroll
    for (int st = 0; st < 4; ++st)
#pragma unroll
        for (int r = 0; r < 4; ++r) spart[st][r] = 0.f;

    for (int j = 0; j < 16; ++j) {  // 16 col-tiles of h
        f32x4 C[4];
#pragma unroll
        for (int st = 0; st < 4; ++st)
#pragma unroll
            for (int r = 0; r < 4; ++r) C[st][r] = 0.f;
#pragma unroll
        for (int kk = 0; kk < 8; ++kk) {
            bf16x8 Bf = *(const bf16x8*)(wfrag +
                        (size_t)((j * 8 + kk) * 64 + lane) * 8);
#pragma unroll
            for (int st = 0; st < 4; ++st)
                C[st] = __builtin_amdgcn_mfma_f32_16x16x32_bf16(
                    A[st][kk], Bf, C[st], 0, 0, 0);
        }
        int n = j * 16 + col;
        float w2n = w2[n];
        float b1n = b1[n];
#pragma unroll
        for (int st = 0; st < 4; ++st)
#pragma unroll
            for (int r = 0; r < 4; ++r) {
                float h = C[st][r] + b1n;
                float ex = __expf(2.f * h);          // tanh = 1 - 2/(e^{2h}+1)
                spart[st][r] += (1.f - 2.f / (ex + 1.f)) * w2n;
            }
    }
    // reduce over the 16 column-lanes; C/D layout: row = quad*4 + r
#pragma unroll
    for (int o = 1; o < 16; o <<= 1)
#pragma unroll
        for (int st = 0; st < 4; ++st)
#pragma unroll
            for (int r = 0; r < 4; ++r)
                spart[st][r] += __shfl_xor(spart[st][r], o, 64);
    if (col == 0) {
#pragma unroll
        for (int st = 0; st < 4; ++st)
#pragma unroll
            for (int r = 0; r < 4; ++r) {
                long row = base + st * 16 + quad * 4 + r;
                e_lds[row - bb] = (row < N) ? __expf(spart[st][r]) : 0.f;
            }
    }
    __syncthreads();

    // ---- Phase 2: pooling. thread t = feature t; rows are contiguous. ----
    {
        const int t = threadIdx.x;
        float acc = 0.f, acc_e = 0.f;
#pragma unroll 4
        for (int i = 0; i < 256; ++i) {
            long row = bb + i; if (row >= N) row = N - 1;   // e=0 for pads
            float e  = e_lds[i];
            float xv = x[row * (long)D + t];                // L3-hot re-read
            acc   += e * xv;
            acc_e += e;
            bool flush = (i == 255) || (batch_lds[i + 1] != batch_lds[i]);
            if (flush) {   // wave-uniform
                int seg = batch_lds[i];
                atomicAdd(&pooled_raw[(size_t)seg * D + t], acc);
                if (t == 0) atomicAdd(&denom[seg], acc_e);
                acc = 0.f; acc_e = 0.f;
            }
        }
    }
}

// ---------------------------------------------------------------------------
// out = (pooled_raw * 1/denom) @ Wp + bp. 8 rows/block; P staged transposed.
__global__ __launch_bounds__(256) void out_gemm_kernel(
    const float* __restrict__ pooled_raw, const float* __restrict__ denom,
    const float* __restrict__ Wp, const float* __restrict__ bp,
    float* __restrict__ out) {
    constexpr int GR = 8;
    int rb = blockIdx.x * GR;
    int j = threadIdx.x;
    __shared__ float P[D * GR];  // [k][r]
    __shared__ float dv[GR];
    if (j < GR) {
        float d = denom[rb + j];
        dv[j] = d > 0.f ? 1.f / d : 0.f;
    }
    __syncthreads();
    for (int i = threadIdx.x; i < GR * D; i += 256) {
        int r = i >> 8, k = i & 255;
        P[k * GR + r] = pooled_raw[(size_t)(rb + r) * D + k] * dv[r];
    }
    __syncthreads();
    float acc[GR];
#pragma unroll
    for (int r = 0; r < GR; ++r) acc[r] = 0.f;
    for (int k = 0; k < D; ++k) {
        float w = Wp[(size_t)k * D + j];
        const float4* p4 = (const float4*)(&P[k * GR]);
        float4 a = p4[0], c = p4[1];
        acc[0] += a.x * w; acc[1] += a.y * w; acc[2] += a.z * w; acc[3] += a.w * w;
        acc[4] += c.x * w; acc[5] += c.y * w; acc[6] += c.z * w; acc[7] += c.w * w;
    }
    float bj = bp[j];
#pragma unroll
    for (int r = 0; r < GR; ++r) out[(size_t)(rb + r) * D + j] = acc[r] + bj;
}

// ---------------------------------------------------------------------------
extern "C" void kernel_launch(void* const* d_in, const int* in_sizes, int n_in,
                              void* d_out, int out_size, void* d_ws, size_t ws_size,
                              hipStream_t stream) {
    const float* x     = (const float*)d_in[0];
    const int*   batch = (const int*)d_in[1];
    const float* W1    = (const float*)d_in[2];
    const float* b1    = (const float*)d_in[3];
    const float* w2    = (const float*)d_in[4];
    // d_in[5] = b2: constant shift, cancels in softmax — unused.
    const float* Wp    = (const float*)d_in[6];
    const float* bp    = (const float*)d_in[7];
    float* out = (float*)d_out;
    const int N = in_sizes[1];      // 1,000,000
    const int B = out_size / D;     // 4096

    // ws layout: wfrag(128KB) | pooled_raw(4*B*D) | denom(4*B)
    char* w = (char*)d_ws;
    bf16_t* wfrag = (bf16_t*)w;
    float* pooled_raw = (float*)(w + 131072);
    float* denom = (float*)(w + 131072 + (size_t)4 * B * D);

    int zthreads = B * D / 4;                       // 262144
    hipLaunchKernelGGL(prep_kernel, dim3((zthreads + 255) / 256), dim3(256), 0,
                       stream, W1, wfrag, pooled_raw, denom, B);
    int nb = (N + 255) / 256;
    hipLaunchKernelGGL(fused_kernel, dim3(nb), dim3(256), 0, stream,
                       x, batch, wfrag, b1, w2, pooled_raw, denom, N);
    hipLaunchKernelGGL(out_gemm_kernel, dim3(B / 8), dim3(256), 0, stream,
                       pooled_raw, denom, Wp, bp, out);
}